// Round 14
// baseline (381.975 us; speedup 1.0000x reference)
//
#include <hip/hip_runtime.h>
#include <math.h>

// ---------------------------------------------------------------------------
// Problem constants
// ---------------------------------------------------------------------------
#define HD 2048      // hidden size h
#define NQH 16       // num q heads
#define NKVH 4       // num kv heads
#define HEADD 128    // head dim
#define QKVN 3072    // qkv cols
#define NEXP 16      // experts
#define EI 512       // expert intermediate
#define SSI 1024     // shared intermediate
#define TOPK 4
#define TT 1024      // tokens

typedef __bf16 bf16x8 __attribute__((ext_vector_type(8)));
typedef float f32x4 __attribute__((ext_vector_type(4)));
typedef unsigned short u16x8 __attribute__((ext_vector_type(8)));
typedef unsigned short u16x4 __attribute__((ext_vector_type(4)));

static __device__ __forceinline__ unsigned short f2bf(float f) {
    union { float f; unsigned int u; } v; v.f = f;
    unsigned int r = v.u + 0x7fff + ((v.u >> 16) & 1);
    return (unsigned short)(r >> 16);
}

static __device__ __forceinline__ void gl_lds16(const unsigned short* g,
                                                unsigned short* l) {
    __builtin_amdgcn_global_load_lds(
        (const __attribute__((address_space(1))) unsigned int*)g,
        (__attribute__((address_space(3))) unsigned int*)l, 16, 0, 0);
}

// ---------------------------------------------------------------------------
// Fused add + RMSNorm. resid_out(f32 opt) ; x_bf (bf16)
// ---------------------------------------------------------------------------
__global__ __launch_bounds__(256) void add_rmsnorm_kernel(
    const float* __restrict__ a, const float* __restrict__ b,
    const float* __restrict__ w, float* __restrict__ resid_out,
    unsigned short* __restrict__ x_bf)
{
    int t = blockIdx.x;
    int tid = threadIdx.x;
    const float4* a4 = (const float4*)(a + (size_t)t * HD);
    const float4* b4 = b ? (const float4*)(b + (size_t)t * HD) : nullptr;
    float4* r4 = resid_out ? (float4*)(resid_out + (size_t)t * HD) : nullptr;
    const float4* w4 = (const float4*)w;

    float4 v[2];
    float ss = 0.f;
#pragma unroll
    for (int l = 0; l < 2; ++l) {
        int idx = tid + l * 256;
        float4 va = a4[idx];
        if (b4) {
            float4 vb = b4[idx];
            va.x += vb.x; va.y += vb.y; va.z += vb.z; va.w += vb.w;
        }
        if (r4) r4[idx] = va;
        v[l] = va;
        ss += va.x * va.x + va.y * va.y + va.z * va.z + va.w * va.w;
    }
    for (int off = 32; off > 0; off >>= 1) ss += __shfl_down(ss, off);
    __shared__ float red[4];
    int lane = tid & 63, wv = tid >> 6;
    if (lane == 0) red[wv] = ss;
    __syncthreads();
    if (tid == 0) {
        float s = red[0] + red[1] + red[2] + red[3];
        red[0] = rsqrtf(s / (float)HD + 1e-6f);
    }
    __syncthreads();
    float inv = red[0];
#pragma unroll
    for (int l = 0; l < 2; ++l) {
        int idx = tid + l * 256;
        float4 va = v[l], vw = w4[idx];
        ushort4 ob;
        ob.x = f2bf(va.x * inv * vw.x);
        ob.y = f2bf(va.y * inv * vw.y);
        ob.z = f2bf(va.z * inv * vw.z);
        ob.w = f2bf(va.w * inv * vw.w);
        ((ushort4*)(x_bf + (size_t)t * HD))[idx] = ob;
    }
}

// ---------------------------------------------------------------------------
// Fused: sum 4 split-K partials + resid -> resid2 (f32) ; rmsnorm -> x_bf
// ---------------------------------------------------------------------------
__global__ __launch_bounds__(256) void reduce4_add_rmsnorm(
    const float* __restrict__ part, const float* __restrict__ resid,
    const float* __restrict__ w, float* __restrict__ resid2_out,
    unsigned short* __restrict__ x_bf)
{
    const size_t NP = (size_t)TT * HD / 4;
    int t = blockIdx.x;
    int tid = threadIdx.x;
    const float4* p4 = (const float4*)part;
    const float4* r4 = (const float4*)(resid + (size_t)t * HD);
    float4* o4 = (float4*)(resid2_out + (size_t)t * HD);
    const float4* w4 = (const float4*)w;

    float4 v[2];
    float ss = 0.f;
#pragma unroll
    for (int l = 0; l < 2; ++l) {
        int li = tid + l * 256;
        size_t idx = (size_t)t * (HD / 4) + li;
        float4 s = p4[idx];
        float4 q1 = p4[NP + idx], q2 = p4[2 * NP + idx], q3 = p4[3 * NP + idx];
        float4 rr = r4[li];
        s.x += q1.x + q2.x + q3.x + rr.x;
        s.y += q1.y + q2.y + q3.y + rr.y;
        s.z += q1.z + q2.z + q3.z + rr.z;
        s.w += q1.w + q2.w + q3.w + rr.w;
        o4[li] = s;
        v[l] = s;
        ss += s.x * s.x + s.y * s.y + s.z * s.z + s.w * s.w;
    }
    for (int off = 32; off > 0; off >>= 1) ss += __shfl_down(ss, off);
    __shared__ float red[4];
    int lane = tid & 63, wv = tid >> 6;
    if (lane == 0) red[wv] = ss;
    __syncthreads();
    if (tid == 0) {
        float s = red[0] + red[1] + red[2] + red[3];
        red[0] = rsqrtf(s / (float)HD + 1e-6f);
    }
    __syncthreads();
    float inv = red[0];
#pragma unroll
    for (int l = 0; l < 2; ++l) {
        int li = tid + l * 256;
        float4 va = v[l], vw = w4[li];
        ushort4 ob;
        ob.x = f2bf(va.x * inv * vw.x);
        ob.y = f2bf(va.y * inv * vw.y);
        ob.z = f2bf(va.z * inv * vw.z);
        ob.w = f2bf(va.w * inv * vw.w);
        ((ushort4*)(x_bf + (size_t)t * HD))[li] = ob;
    }
}

// ---------------------------------------------------------------------------
// Transpose + convert v2: f32 in [K][N] -> bf16 out [N][K]  (per-z strides)
// ---------------------------------------------------------------------------
__global__ __launch_bounds__(256) void transpose_convert(
    const float* __restrict__ in, unsigned short* __restrict__ out,
    int K, int N, long long strideIn, long long strideOut)
{
    __shared__ float tile[64][33];
    const int n0 = blockIdx.x * 32;
    const int k0 = blockIdx.y * 64;
    const float* ip = in + (size_t)blockIdx.z * strideIn;
    unsigned short* op = out + (size_t)blockIdx.z * strideOut;
    int tid = threadIdx.x;
    int c = (tid & 7) * 4;
#pragma unroll
    for (int i = 0; i < 2; ++i) {
        int r = (tid >> 3) + i * 32;
        float4 v = *(const float4*)(ip + (size_t)(k0 + r) * N + n0 + c);
        tile[r][c] = v.x; tile[r][c + 1] = v.y;
        tile[r][c + 2] = v.z; tile[r][c + 3] = v.w;
    }
    __syncthreads();
    int rr = tid >> 3;
    int kc = (tid & 7) * 8;
    u16x8 o;
#pragma unroll
    for (int j = 0; j < 8; ++j) o[j] = f2bf(tile[kc + j][rr]);
    *(u16x8*)(op + (size_t)(n0 + rr) * K + k0 + kc) = o;
}

// ---------------------------------------------------------------------------
// Split-K bf16 MFMA GEMM, STAGE-early double-buffered, BK=64,
// T4 counted-vmcnt (8 loads/stage stay in flight across raw barriers).
// ---------------------------------------------------------------------------
#define SBK 64

__global__ __launch_bounds__(256) void gemm_splitk(
    const unsigned short* __restrict__ A, const unsigned short* __restrict__ B,
    float* __restrict__ Cpart, int M, int N, int Kc, int ldA, int ldB)
{
    __shared__ unsigned short As[2][128 * SBK];
    __shared__ unsigned short Bs[2][128 * SBK];

    const int tid = threadIdx.x;
    const int wave = tid >> 6;
    const int lane = tid & 63;
    const int wr = wave >> 1, wc = wave & 1;
    const int l15 = lane & 15;
    const int row0 = blockIdx.y * 128;
    const int col0 = blockIdx.x * 128;
    const int z = blockIdx.z;

    const unsigned short* Ap = A + (size_t)row0 * ldA + (size_t)z * Kc;
    const unsigned short* Bp = B + (size_t)col0 * ldB + (size_t)z * Kc;

    const int r_st = tid >> 3;
    const int q_st = tid & 7;
    const int csrc = (q_st ^ (r_st & 7)) << 3;

    f32x4 acc[4][4] = {};

    const int nsteps = Kc / SBK;

#define STAGE_SK(buf, k0s)                                                    \
    {                                                                         \
        _Pragma("unroll")                                                     \
        for (int i = 0; i < 4; ++i) {                                         \
            int rr = r_st + i * 32;                                           \
            gl_lds16(Ap + (size_t)rr * ldA + (k0s) + csrc,                    \
                     &As[buf][rr * SBK + q_st * 8]);                          \
            gl_lds16(Bp + (size_t)rr * ldB + (k0s) + csrc,                    \
                     &Bs[buf][rr * SBK + q_st * 8]);                          \
        }                                                                     \
    }

    STAGE_SK(0, 0);

    for (int s = 0; s < nsteps; ++s) {
        const int cur = s & 1;
        if (s + 1 < nsteps) {
            STAGE_SK(cur ^ 1, (s + 1) * SBK);
            asm volatile("s_waitcnt vmcnt(8)" ::: "memory");
        } else {
            asm volatile("s_waitcnt vmcnt(0)" ::: "memory");
        }
        __builtin_amdgcn_s_barrier();

#pragma unroll
        for (int half = 0; half < 2; ++half) {
            const int q = half * 4 + (lane >> 4);
            bf16x8 af[4], bfv[4];
#pragma unroll
            for (int i = 0; i < 4; ++i) {
                int R = wr * 64 + i * 16 + l15;
                af[i] = *(const bf16x8*)&As[cur][R * SBK + ((q ^ (R & 7)) << 3)];
            }
#pragma unroll
            for (int j = 0; j < 4; ++j) {
                int R = wc * 64 + j * 16 + l15;
                bfv[j] = *(const bf16x8*)&Bs[cur][R * SBK + ((q ^ (R & 7)) << 3)];
            }
#pragma unroll
            for (int mi = 0; mi < 4; ++mi)
#pragma unroll
                for (int nj = 0; nj < 4; ++nj)
                    acc[mi][nj] = __builtin_amdgcn_mfma_f32_16x16x32_bf16(
                        af[mi], bfv[nj], acc[mi][nj], 0, 0, 0);
        }
        __builtin_amdgcn_s_barrier();
    }

    float* Cp = Cpart + (size_t)z * M * N;
#pragma unroll
    for (int mi = 0; mi < 4; ++mi)
#pragma unroll
        for (int nj = 0; nj < 4; ++nj)
#pragma unroll
            for (int r = 0; r < 4; ++r) {
                int row = row0 + wr * 64 + mi * 16 + (lane >> 4) * 4 + r;
                int col = col0 + wc * 64 + nj * 16 + l15;
                Cp[(size_t)row * N + col] = acc[mi][nj][r];
            }
}

// ---------------------------------------------------------------------------
// Reduce split-K partials: out = sum_z part[z] (+ add) (+= out if acc)
// ---------------------------------------------------------------------------
__global__ __launch_bounds__(256) void reduce_partials(
    const float* __restrict__ part, int ns, int n4,
    const float* __restrict__ add, float* __restrict__ out, int acc)
{
    const float4* p4 = (const float4*)part;
    const float4* a4 = (const float4*)add;
    float4* o4 = (float4*)out;
    for (int idx = blockIdx.x * 256 + threadIdx.x; idx < n4;
         idx += gridDim.x * 256) {
        float4 s = p4[idx];
        for (int z = 1; z < ns; ++z) {
            float4 q = p4[(size_t)z * n4 + idx];
            s.x += q.x; s.y += q.y; s.z += q.z; s.w += q.w;
        }
        if (add) {
            float4 q = a4[idx];
            s.x += q.x; s.y += q.y; s.z += q.z; s.w += q.w;
        }
        if (acc) {
            float4 q = o4[idx];
            s.x += q.x; s.y += q.y; s.z += q.z; s.w += q.w;
        }
        o4[idx] = s;
    }
}

// ---------------------------------------------------------------------------
// Reduce split-K partials of shared-expert gu [T][2048] + SwiGLU -> bf16
// ---------------------------------------------------------------------------
__global__ __launch_bounds__(256) void reduce_swiglu(
    const float* __restrict__ part, int ns, unsigned short* __restrict__ out)
{
    int idx4 = blockIdx.x * 256 + threadIdx.x;
    int t = idx4 >> 8;
    int i4 = (idx4 & 255) * 4;
    const float4* pg = (const float4*)(part + (size_t)t * (2 * SSI) + i4);
    const float4* pu = (const float4*)(part + (size_t)t * (2 * SSI) + SSI + i4);
    float4 g = pg[0], u = pu[0];
    for (int z = 1; z < ns; ++z) {
        float4 g2 = *(const float4*)((const float*)pg + (size_t)z * TT * 2 * SSI);
        float4 u2 = *(const float4*)((const float*)pu + (size_t)z * TT * 2 * SSI);
        g.x += g2.x; g.y += g2.y; g.z += g2.z; g.w += g2.w;
        u.x += u2.x; u.y += u2.y; u.z += u2.z; u.w += u2.w;
    }
    ushort4 o;
    o.x = f2bf((g.x / (1.f + __expf(-g.x))) * u.x);
    o.y = f2bf((g.y / (1.f + __expf(-g.y))) * u.y);
    o.z = f2bf((g.z / (1.f + __expf(-g.z))) * u.z);
    o.w = f2bf((g.w / (1.f + __expf(-g.w))) * u.w);
    *(ushort4*)(out + (size_t)t * SSI + i4) = o;
}

// ---------------------------------------------------------------------------
// Build per-expert token lists + slot ranks (token-ordered, deterministic).
// ---------------------------------------------------------------------------
__global__ __launch_bounds__(256) void build_lists(
    const float* __restrict__ comb, int* __restrict__ lists,
    int* __restrict__ slots, int* __restrict__ cnts)
{
    int e = blockIdx.x;
    int tid = threadIdx.x;
    __shared__ int sc[256];
    int loc[4];
    int c = 0;
#pragma unroll
    for (int j = 0; j < 4; ++j) {
        int t = tid * 4 + j;
        if (comb[(size_t)t * NEXP + e] > 0.f) loc[c++] = t;
    }
    sc[tid] = c;
    __syncthreads();
    for (int off = 1; off < 256; off <<= 1) {
        int v = (tid >= off) ? sc[tid - off] : 0;
        __syncthreads();
        sc[tid] += v;
        __syncthreads();
    }
    int base = sc[tid] - c;
    for (int i = 0; i < c; ++i) {
        int t = loc[i];
        int s = 0;
        for (int e2 = 0; e2 < e; ++e2)
            s += (comb[(size_t)t * NEXP + e2] > 0.f) ? 1 : 0;
        lists[e * TT + base + i] = t;
        slots[e * TT + base + i] = s;
    }
    if (tid == 255) cnts[e] = sc[255];
}

// ---------------------------------------------------------------------------
// Prefix-scan expert counts -> bases[17]
// ---------------------------------------------------------------------------
__global__ void scan_cnts(const int* __restrict__ cnts, int* __restrict__ bases)
{
    if (threadIdx.x == 0 && blockIdx.x == 0) {
        int a = 0;
        for (int e = 0; e < NEXP; ++e) { bases[e] = a; a += cnts[e]; }
        bases[NEXP] = a;
    }
}

// ---------------------------------------------------------------------------
// Sparse MoE expert-up reading f32 weights DIRECTLY (no transpose pass).
// Per K-step: B f32 tiles loaded to regs early, converted+transposed into
// XOR-swizzled 8B-chunk LDS after MFMA (T14 issue-early/write-late).
// A staged via global_load_lds as before.  grid (8 n-blocks, 16 m, 16 e).
// ---------------------------------------------------------------------------
__global__ __launch_bounds__(256) void moe_up_f32(
    const unsigned short* __restrict__ x2B,
    const float* __restrict__ w13,            // [e][k=2048][n=1024]
    const float* __restrict__ comb,
    const int* __restrict__ lists,
    const int* __restrict__ cnts,
    const int* __restrict__ bases,
    unsigned short* __restrict__ actC)
{
    __shared__ unsigned short As[2][64 * 64];
    __shared__ unsigned short Bgs[2][64 * 64];   // [n_loc][16 chunks x 4 u16], swz
    __shared__ unsigned short Bus[2][64 * 64];

    const int e = blockIdx.z;
    const int cnt = cnts[e];
    const int m0 = blockIdx.y * 64;
    if (m0 >= cnt) return;
    const int n0 = blockIdx.x * 64;
    const int base_e = bases[e];

    const int tid = threadIdx.x;
    const int w = tid >> 6;
    const int lane = tid & 63;
    const int l15 = lane & 15;
    const int g = lane >> 4;

    // A staging coords (as in prior moe_up)
    const int r0 = tid >> 3;
    const int q_st = tid & 7;
    const int swz = (q_st ^ (r0 & 7)) << 3;

    int a0 = m0 + r0, a1 = m0 + r0 + 32;
    int tok0 = lists[e * TT + (a0 < cnt ? a0 : cnt - 1)];
    int tok1 = lists[e * TT + (a1 < cnt ? a1 : cnt - 1)];
    const unsigned short* Asrc0 = x2B + (size_t)tok0 * HD;
    const unsigned short* Asrc1 = x2B + (size_t)tok1 * HD;

    // B load coords: rows kb+j (j=0..3), cols n0g+bn4..+3
    const int bkb = (tid >> 4) * 4;           // 0..60
    const int bn4 = (tid & 15) * 4;           // 0..60
    const float* Wg = w13 + (size_t)e * HD * 1024 + n0 + bn4;
    const float* Wu = Wg + 512;

    f32x4 ag[4] = {};
    f32x4 au[4] = {};

    float4 bg4[4], bu4[4];

#define STAGE_A_UP(buf, k0s)                                                  \
    {                                                                         \
        gl_lds16(Asrc0 + (k0s) + swz, &As[buf][(tid) * 8]);                   \
        gl_lds16(Asrc1 + (k0s) + swz, &As[buf][(tid + 256) * 8]);             \
    }

#define LOADB_UP(k0s)                                                         \
    {                                                                         \
        _Pragma("unroll")                                                     \
        for (int j = 0; j < 4; ++j) {                                         \
            bg4[j] = *(const float4*)(Wg + (size_t)((k0s) + bkb + j) * 1024); \
            bu4[j] = *(const float4*)(Wu + (size_t)((k0s) + bkb + j) * 1024); \
        }                                                                     \
    }

#define CVTWRITE_UP(buf)                                                      \
    {                                                                         \
        _Pragma("unroll")                                                     \
        for (int i = 0; i < 4; ++i) {                                         \
            int nl = bn4 + i;                                                 \
            int c8 = (tid >> 4) ^ (nl & 15);                                  \
            u16x4 pg, pu;                                                     \
            pg[0] = f2bf(((const float*)&bg4[0])[i]);                         \
            pg[1] = f2bf(((const float*)&bg4[1])[i]);                         \
            pg[2] = f2bf(((const float*)&bg4[2])[i]);                         \
            pg[3] = f2bf(((const float*)&bg4[3])[i]);                         \
            pu[0] = f2bf(((const float*)&bu4[0])[i]);                         \
            pu[1] = f2bf(((const float*)&bu4[1])[i]);                         \
            pu[2] = f2bf(((const float*)&bu4[2])[i]);                         \
            pu[3] = f2bf(((const float*)&bu4[3])[i]);                         \
            *(u16x4*)&Bgs[buf][(nl * 16 + c8) * 4] = pg;                      \
            *(u16x4*)&Bus[buf][(nl * 16 + c8) * 4] = pu;                      \
        }                                                                     \
    }

    const int nsteps = HD / 64;   // 32

    // prologue: fill buffer 0
    STAGE_A_UP(0, 0);
    LOADB_UP(0);
    asm volatile("s_waitcnt vmcnt(0)" ::: "memory");
    CVTWRITE_UP(0);
    asm volatile("s_waitcnt lgkmcnt(0)" ::: "memory");
    __builtin_amdgcn_s_barrier();

    for (int s = 0; s < nsteps; ++s) {
        const int cur = s & 1;
        if (s + 1 < nsteps) {
            STAGE_A_UP(cur ^ 1, (s + 1) * 64);
            LOADB_UP((s + 1) * 64);
        }

        // ---- compute on cur ----
#pragma unroll
        for (int kk2 = 0; kk2 < 2; ++kk2) {
            const int q = kk2 * 4 + g;
            bf16x8 af[4];
#pragma unroll
            for (int i = 0; i < 4; ++i) {
                int R = i * 16 + l15;
                af[i] = *(const bf16x8*)&As[cur][R * 64 + ((q ^ (R & 7)) << 3)];
            }
            const int Rb = w * 16 + l15;
            union { u16x4 h[2]; bf16x8 v; } ubg, ubu;
            ubg.h[0] = *(const u16x4*)&Bgs[cur][(Rb * 16 + ((2 * q) ^ l15)) * 4];
            ubg.h[1] = *(const u16x4*)&Bgs[cur][(Rb * 16 + ((2 * q + 1) ^ l15)) * 4];
            ubu.h[0] = *(const u16x4*)&Bus[cur][(Rb * 16 + ((2 * q) ^ l15)) * 4];
            ubu.h[1] = *(const u16x4*)&Bus[cur][(Rb * 16 + ((2 * q + 1) ^ l15)) * 4];
#pragma unroll
            for (int mi = 0; mi < 4; ++mi) {
                ag[mi] = __builtin_amdgcn_mfma_f32_16x16x32_bf16(
                    af[mi], ubg.v, ag[mi], 0, 0, 0);
                au[mi] = __builtin_amdgcn_mfma_f32_16x16x32_bf16(
                    af[mi], ubu.v, au[mi], 0, 0, 0);
            }
        }

        if (s + 1 < nsteps) {
            asm volatile("s_waitcnt vmcnt(0)" ::: "memory");
            CVTWRITE_UP(cur ^ 1);
            asm volatile("s_waitcnt lgkmcnt(0)" ::: "memory");
        }
        __builtin_amdgcn_s_barrier();
    }

#pragma unroll
    for (int mi = 0; mi < 4; ++mi) {
#pragma unroll
        for (int r = 0; r < 4; ++r) {
            int grow = m0 + mi * 16 + g * 4 + r;
            if (grow >= cnt) continue;
            int tok = lists[e * TT + grow];
            float cw = comb[(size_t)tok * NEXP + e];
            int col = n0 + w * 16 + l15;
            float gg = ag[mi][r];
            float uu = au[mi][r];
            float v = (gg / (1.f + __expf(-gg))) * uu * cw;
            actC[(size_t)(base_e + grow) * EI + col] = f2bf(v);
        }
    }
}

// ---------------------------------------------------------------------------
// Sparse MoE down: actC @ w2T-slice -> slot partials (f32).
// 2-buffer T4 counted-vmcnt (6 loads/stage in flight), 48 KB LDS.
// ---------------------------------------------------------------------------
__global__ __launch_bounds__(256) void moe_down_gather(
    const unsigned short* __restrict__ actC,
    const unsigned short* __restrict__ w2T,   // [HD][NEXP*EI]
    const int* __restrict__ lists,
    const int* __restrict__ slots,
    const int* __restrict__ cnts,
    const int* __restrict__ bases,
    float* __restrict__ slotpart)
{
    __shared__ unsigned short As[2][64 * 64];
    __shared__ unsigned short Bs[2][128 * 64];

    const int e = blockIdx.z;
    const int cnt = cnts[e];
    const int m0 = blockIdx.y * 64;
    if (m0 >= cnt) return;
    const int n0 = blockIdx.x * 128;
    const int base_e = bases[e];

    const int tid = threadIdx.x;
    const int w = tid >> 6;
    const int lane = tid & 63;
    const int l15 = lane & 15;
    const int g = lane >> 4;

    const int r0 = tid >> 3;
    const int q_st = tid & 7;
    const int swz = (q_st ^ (r0 & 7)) << 3;

    int a0 = m0 + r0, a1 = m0 + r0 + 32;
    const unsigned short* Asrc0 =
        actC + (size_t)(base_e + (a0 < cnt ? a0 : cnt - 1)) * EI;
    const unsigned short* Asrc1 =
        actC + (size_t)(base_e + (a1 < cnt ? a1 : cnt - 1)) * EI;
    const unsigned short* Bbase = w2T + (size_t)e * EI;

#define STAGE_DN(buf, k0s)                                                    \
    {                                                                         \
        gl_lds16(Asrc0 + (k0s) + swz, &As[buf][(tid) * 8]);                   \
        gl_lds16(Asrc1 + (k0s) + swz, &As[buf][(tid + 256) * 8]);             \
        _Pragma("unroll")                                                     \
        for (int i = 0; i < 4; ++i) {                                         \
            int rr = r0 + i * 32;                                             \
            gl_lds16(Bbase + (size_t)(n0 + rr) * (NEXP * EI) + (k0s) + swz,   \
                     &Bs[buf][(tid + i * 256) * 8]);                          \
        }                                                                     \
    }

    f32x4 acc[4][2] = {};

    STAGE_DN(0, 0);

    const int nsteps = EI / 64;
    for (int s = 0; s < nsteps; ++s) {
        const int cur = s & 1;
        if (s + 1 < nsteps) {
            STAGE_DN(cur ^ 1, (s + 1) * 64);
            asm volatile("s_waitcnt vmcnt(6)" ::: "memory");
        } else {
            asm volatile("s_waitcnt vmcnt(0)" ::: "memory");
        }
        __builtin_amdgcn_s_barrier();

#pragma unroll
        for (int kk2 = 0; kk2 < 2; ++kk2) {
            const int q = kk2 * 4 + g;
            bf16x8 af[4], bf[2];
#pragma unroll
            for (int i = 0; i < 4; ++i) {
                int R = i * 16 + l15;
                af[i] = *(const bf16x8*)&As[cur][R * 64 + ((q ^ (R & 7)) << 3)];
            }
#pragma unroll
            for (int j = 0; j < 2; ++j) {
                int R = w * 32 + j * 16 + l15;
                bf[j] = *(const bf16x8*)&Bs[cur][R * 64 + ((q ^ (R & 7)) << 3)];
            }
#pragma unroll
            for (int mi = 0; mi < 4; ++mi)
#pragma unroll
                for (int nj = 0; nj < 2; ++nj)
                    acc[mi][nj] = __builtin_amdgcn_mfma_f32_16x16x32_bf16(
                        af[mi], bf[nj], acc[mi][nj], 0, 0, 0);
        }
        __builtin_amdgcn_s_barrier();
    }

#pragma unroll
    for (int mi = 0; mi < 4; ++mi) {
#pragma unroll
        for (int r = 0; r < 4; ++r) {
            int grow = m0 + mi * 16 + g * 4 + r;
            if (grow >= cnt) continue;
            int tok = lists[e * TT + grow];
            int sl  = slots[e * TT + grow];
            float* orow = slotpart + (size_t)sl * TT * HD + (size_t)tok * HD;
#pragma unroll
            for (int nj = 0; nj < 2; ++nj) {
                int col = n0 + w * 32 + nj * 16 + l15;
                orow[col] = acc[mi][nj][r];
            }
        }
    }
}

// ---------------------------------------------------------------------------
// RoPE + pack to head-major bf16, fused qkv split-K reduce (2 partials).
// ---------------------------------------------------------------------------
__global__ __launch_bounds__(256) void rope_pack(
    const float* __restrict__ qkv0, const float* __restrict__ qkv1,
    const int* __restrict__ pos_ids,
    unsigned short* __restrict__ Qb, unsigned short* __restrict__ Kb,
    unsigned short* __restrict__ Vb)
{
    const float SCALE = 0.08838834764831843f;
    int t = blockIdx.x;
    int tid = threadIdx.x;
    int w = tid >> 6, lane = tid & 63;
    float pos = (float)pos_ids[t];
    float invf = powf(10000.0f, -(float)lane * (1.0f / 64.0f));
    float ang = pos * invf;
    float c = cosf(ang);
    float s = sinf(ang);
    const float* row0 = qkv0 + (size_t)t * QKVN;
    const float* row1 = qkv1 + (size_t)t * QKVN;
#pragma unroll
    for (int j = 0; j < 5; ++j) {
        int hh = w * 5 + j;
        const float* hb0 = row0 + hh * HEADD;
        const float* hb1 = row1 + hh * HEADD;
        float x1 = hb0[lane] + hb1[lane];
        float x2 = hb0[lane + 64] + hb1[lane + 64];
        float o1 = x1 * c - x2 * s;
        float o2 = x2 * c + x1 * s;
        if (hh < NQH) {
            unsigned short* qp = Qb + ((size_t)hh * TT + t) * HEADD;
            qp[lane] = f2bf(o1 * SCALE);
            qp[lane + 64] = f2bf(o2 * SCALE);
        } else {
            unsigned short* kp = Kb + ((size_t)(hh - NQH) * TT + t) * HEADD;
            kp[lane] = f2bf(o1);
            kp[lane + 64] = f2bf(o2);
        }
    }
    float2 v0 = *(const float2*)(row0 + 2560 + tid * 2);
    float2 v1 = *(const float2*)(row1 + 2560 + tid * 2);
    int kvh = tid >> 6;
    int d = (tid * 2) & 127;
    unsigned int packed = (unsigned int)f2bf(v0.x + v1.x) |
                          ((unsigned int)f2bf(v0.y + v1.y) << 16);
    *(unsigned int*)(Vb + ((size_t)kvh * TT + t) * HEADD + d) = packed;
}

// ---------------------------------------------------------------------------
// V transpose: Vb[kvh][t][128] -> Vt[kvh][128][t]
// ---------------------------------------------------------------------------
__global__ __launch_bounds__(256) void transpose_v(
    const unsigned short* __restrict__ Vb, unsigned short* __restrict__ Vt)
{
    __shared__ unsigned short tile[32][40];
    const int kvh = blockIdx.z;
    const int t0 = blockIdx.x * 32, d0 = blockIdx.y * 32;
    int tid = threadIdx.x;
    int r = tid >> 3, c4 = (tid & 7) * 4;
    ushort4 v = *(const ushort4*)(Vb + ((size_t)kvh * TT + t0 + r) * HEADD + d0 + c4);
    tile[r][c4] = v.x; tile[r][c4 + 1] = v.y;
    tile[r][c4 + 2] = v.z; tile[r][c4 + 3] = v.w;
    __syncthreads();
    ushort4 o;
    o.x = tile[c4 + 0][r];
    o.y = tile[c4 + 1][r];
    o.z = tile[c4 + 2][r];
    o.w = tile[c4 + 3][r];
    *(ushort4*)(Vt + ((size_t)kvh * HEADD + d0 + r) * TT + t0 + c4) = o;
}

// ---------------------------------------------------------------------------
// MFMA flash attention v2 — LDS-staged K/V, double-buffered, triangle-paired,
// T4 counted-vmcnt (16 loads/stage in flight across raw barriers).
// ---------------------------------------------------------------------------
__global__ __launch_bounds__(128) void flash_attn_mfma(
    const unsigned short* __restrict__ Qb,
    const unsigned short* __restrict__ Kb,
    const unsigned short* __restrict__ Vt,
    unsigned short* __restrict__ ctx)
{
    __shared__ __align__(16) unsigned short Ks[2][64 * 128];
    __shared__ __align__(16) unsigned short Vs[2][128 * 64];
    __shared__ __align__(16) unsigned short Pl[2][16][72];

    const int h   = blockIdx.x;
    const int p   = blockIdx.y;
    const int rh  = blockIdx.z;
    const int kvh = h >> 2;
    const int tid = threadIdx.x;
    const int w   = tid >> 6;
    const int lane = tid & 63;
    const int l15 = lane & 15;
    const int g   = lane >> 4;

    const unsigned short* Kh = Kb + (size_t)kvh * TT * HEADD;
    const unsigned short* Vh = Vt + (size_t)kvh * HEADD * TT;

#define STAGE_KV(buf, s0s)                                                    \
    {                                                                         \
        _Pragma("unroll")                                                     \
        for (int i = 0; i < 8; ++i) {                                         \
            int idx = tid + i * 128;                                          \
            int r = idx >> 4, c = idx & 15;                                   \
            int csw = (c & 8) | ((c ^ r) & 7);                                \
            gl_lds16(Kh + (size_t)((s0s) + r) * HEADD + csw * 8,              \
                     &Ks[buf][idx * 8]);                                      \
        }                                                                     \
        _Pragma("unroll")                                                     \
        for (int i = 0; i < 8; ++i) {                                         \
            int idx = tid + i * 128;                                          \
            int r = idx >> 3, c = idx & 7;                                    \
            int csw = (c ^ r) & 7;                                            \
            gl_lds16(Vh + (size_t)r * TT + (s0s) + csw * 8,                   \
                     &Vs[buf][idx * 8]);                                      \
        }                                                                     \
    }

    const int qts[2] = {p, 15 - p};

#pragma unroll
    for (int qi = 0; qi < 2; ++qi) {
        const int qt = qts[qi];
        const int q0 = qt * 64 + rh * 32 + w * 16;
        const int ntiles = qt + 1;

        const unsigned short* Qrow = Qb + ((size_t)h * TT + q0 + l15) * HEADD;
        bf16x8 qf[4];
#pragma unroll
        for (int kk = 0; kk < 4; ++kk)
            qf[kk] = *(const bf16x8*)(Qrow + kk * 32 + g * 8);

        float m_i[4], l_i[4];
#pragma unroll
        for (int r = 0; r < 4; ++r) { m_i[r] = -1e30f; l_i[r] = 0.f; }
        f32x4 of[8] = {};

        STAGE_KV(0, 0);

        for (int st = 0; st < ntiles; ++st) {
            const int cur = st & 1;
            const int s0 = st * 64;
            if (st + 1 < ntiles) {
                STAGE_KV(cur ^ 1, (st + 1) * 64);
                asm volatile("s_waitcnt vmcnt(16)" ::: "memory");
            } else {
                asm volatile("s_waitcnt vmcnt(0)" ::: "memory");
            }
            __builtin_amdgcn_s_barrier();

            f32x4 sacc[4] = {};
#pragma unroll
            for (int kk = 0; kk < 4; ++kk) {
#pragma unroll
                for (int n = 0; n < 4; ++n) {
                    int R = n * 16 + l15;
                    int cidx = kk * 4 + g;
                    int cs = (cidx & 8) | ((cidx ^ R) & 7);
                    bf16x8 kb = *(const bf16x8*)&Ks[cur][R * 128 + cs * 8];
                    sacc[n] = __builtin_amdgcn_mfma_f32_16x16x32_bf16(
                        qf[kk], kb, sacc[n], 0, 0, 0);
                }
            }

            const bool diag = (st == qt);
            float alpha[4];
#pragma unroll
            for (int r = 0; r < 4; ++r) {
                const int qrow = q0 + g * 4 + r;
                float sv[4] = {sacc[0][r], sacc[1][r], sacc[2][r], sacc[3][r]};
                if (diag) {
#pragma unroll
                    for (int n = 0; n < 4; ++n)
                        if (s0 + n * 16 + l15 > qrow) sv[n] = -1e30f;
                }
                float rm = fmaxf(fmaxf(sv[0], sv[1]), fmaxf(sv[2], sv[3]));
                rm = fmaxf(rm, __shfl_xor(rm, 1));
                rm = fmaxf(rm, __shfl_xor(rm, 2));
                rm = fmaxf(rm, __shfl_xor(rm, 4));
                rm = fmaxf(rm, __shfl_xor(rm, 8));
                float mnew = fmaxf(m_i[r], rm);
                alpha[r] = __expf(m_i[r] - mnew);
                float p0 = __expf(sv[0] - mnew);
                float p1 = __expf(sv[1] - mnew);
                float p2 = __expf(sv[2] - mnew);
                float p3 = __expf(sv[3] - mnew);
                float rs = p0 + p1 + p2 + p3;
                rs += __shfl_xor(rs, 1);
                rs += __shfl_xor(rs, 2);
                rs += __shfl_xor(rs, 4);
                rs += __shfl_xor(rs, 8);
                l_i[r] = l_i[r] * alpha[r] + rs;
                m_i[r] = mnew;
                Pl[w][g * 4 + r][0 * 16 + l15] = f2bf(p0);
                Pl[w][g * 4 + r][1 * 16 + l15] = f2bf(p1);
                Pl[w][g * 4 + r][2 * 16 + l15] = f2bf(p2);
                Pl[w][g * 4 + r][3 * 16 + l15] = f2bf(p3);
            }

#pragma unroll
            for (int nd = 0; nd < 8; ++nd)
#pragma unroll
                for (int r = 0; r < 4; ++r)
                    of[nd][r] *= alpha[r];

#pragma unroll
            for (int kk2 = 0; kk2 < 2; ++kk2) {
                bf16x8 pa = *(const bf16x8*)&Pl[w][l15][kk2 * 32 + g * 8];
#pragma unroll
                for (int nd = 0; nd < 8; ++nd) {
                    int R = nd * 16 + l15;
                    int cidx = kk2 * 4 + g;
                    int cs = (cidx ^ R) & 7;
                    bf16x8 vb = *(const bf16x8*)&Vs[cur][R * 64 + cs * 8];
                    of[nd] = __builtin_amdgcn_mfma_f32_16x16x32_bf16(
                        pa, vb, of[nd], 0, 0, 0);
                }
            }
            __builtin_amdgcn_s_barrier();
        }

        float invl[4];
#pragma unroll
        for (int r = 0; r < 4; ++r) invl[r] = 1.f / l_i[r];
#pragma unroll
        for (int nd = 0; nd < 8; ++nd)
#pragma unroll
            for (int r = 0; r < 4; ++r) {
                int trow = q0 + g * 4 + r;
                ctx[(size_t)trow * (NQH * HEADD) + h * HEADD + nd * 16 + l15] =
                    f2bf(of[nd][r] * invl[r]);
            }
    }
}

// ---------------------------------------------------------------------------
// Fused router: rmsnorm(resid2)*w . gate_w, softmax top-4 -> comb (T,16)
// ---------------------------------------------------------------------------
__global__ __launch_bounds__(256) void router_fused(
    const float* __restrict__ resid2, const float* __restrict__ w,
    const float* __restrict__ gate_w, float* __restrict__ comb)
{
    int t = blockIdx.x;
    int tid = threadIdx.x;
    int lane = tid & 63, wv = tid >> 6;

    const float4* r4 = (const float4*)(resid2 + (size_t)t * HD);
    float4 xa = r4[tid * 2], xb = r4[tid * 2 + 1];
    float ss = xa.x * xa.x + xa.y * xa.y + xa.z * xa.z + xa.w * xa.w +
               xb.x * xb.x + xb.y * xb.y + xb.z * xb.z + xb.w * xb.w;
    for (int off = 32; off > 0; off >>= 1) ss += __shfl_down(ss, off);
    __shared__ float red[4];
    if (lane == 0) red[wv] = ss;
    __syncthreads();
    float inv = rsqrtf((red[0] + red[1] + red[2] + red[3]) / (float)HD + 1e-6f);

    const float4* w4 = (const float4*)w;
    float4 wa = w4[tid * 2], wb = w4[tid * 2 + 1];
    float xs[8] = {xa.x * wa.x * inv, xa.y * wa.y * inv, xa.z * wa.z * inv,
                   xa.w * wa.w * inv, xb.x * wb.x * inv, xb.y * wb.y * inv,
                   xb.z * wb.z * inv, xb.w * wb.w * inv};

    float acc[16] = {};
    int kbase = tid * 8;
#pragma unroll
    for (int j = 0; j < 8; ++j) {
        float xv = xs[j];
        const float4* wrow = (const float4*)(gate_w + (size_t)(kbase + j) * NEXP);
        float4 w0 = wrow[0], w1 = wrow[1], w2 = wrow[2], w3 = wrow[3];
        acc[0] += xv * w0.x;  acc[1] += xv * w0.y;  acc[2] += xv * w0.z;  acc[3] += xv * w0.w;
        acc[4] += xv * w1.x;  acc[5] += xv * w1.y;  acc[6] += xv * w1.z;  acc[7] += xv * w1.w;
        acc[8] += xv * w2.x;  acc[9] += xv * w2.y;  acc[10] += xv * w2.z; acc[11] += xv * w2.w;
        acc[12] += xv * w3.x; acc[13] += xv * w3.y; acc[14] += xv * w3.z; acc[15] += xv * w3.w;
    }
    __shared__ float red2[4][16];
#pragma unroll
    for (int e = 0; e < 16; ++e) {
        float v = acc[e];
        v += __shfl_xor(v, 1);
        v += __shfl_xor(v, 2);
        v += __shfl_xor(v, 4);
        v += __shfl_xor(v, 8);
        v += __shfl_xor(v, 16);
        v += __shfl_xor(v, 32);
        if (lane == 0) red2[wv][e] = v;
    }
    __syncthreads();

    if (tid == 0) {
        float l[NEXP];
#pragma unroll
        for (int e = 0; e < NEXP; ++e)
            l[e] = red2[0][e] + red2[1][e] + red2[2][e] + red2[3][e];
        int sel[TOPK];
        float selv[TOPK];
        bool used[NEXP] = {};
#pragma unroll
        for (int r = 0; r < TOPK; ++r) {
            int best = -1;
            float bv = -1e30f;
            for (int e = 0; e < NEXP; ++e)
                if (!used[e] && l[e] > bv) { bv = l[e]; best = e; }
            used[best] = true;
            sel[r] = best;
            selv[r] = bv;
        }
        float mx = selv[0];
        float wsum = 0.f, wvv[TOPK];
#pragma unroll
        for (int r = 0; r < TOPK; ++r) { wvv[r] = __expf(selv[r] - mx); wsum += wvv[r]; }
        float out16[NEXP] = {};
#pragma unroll
        for (int r = 0; r < TOPK; ++r) out16[sel[r]] = wvv[r] / wsum;
#pragma unroll
        for (int e = 0; e < NEXP; ++e) comb[(size_t)t * NEXP + e] = out16[e];
    }
}

// ---------------------------------------------------------------------------
extern "C" void kernel_launch(void* const* d_in, const int* in_sizes, int n_in,
                              void* d_out, int out_size, void* d_ws, size_t ws_size,
                              hipStream_t stream)
{
    const float* hidden   = (const float*)d_in[0];
    const float* residual = (const float*)d_in[1];
    const float* rms1_w   = (const float*)d_in[2];
    const float* rms2_w   = (const float*)d_in[3];
    const float* w_qkv    = (const float*)d_in[4];
    const float* w_dense  = (const float*)d_in[5];
    const float* gate_w   = (const float*)d_in[6];
    const float* w13      = (const float*)d_in[7];
    const float* w2       = (const float*)d_in[8];
    const float* sw13     = (const float*)d_in[9];
    const float* sw2      = (const float*)d_in[10];
    const int*   pos_ids  = (const int*)d_in[11];

    const int T = TT;

    float* out0 = (float*)d_out;
    float* out1 = (float*)d_out + (size_t)T * HD;

    // ---- workspace layout (same as R13) ----
    char* base = (char*)d_ws;
    float*          residF = (float*)(base);                    //  8.39 MB
    unsigned short* xB     = (unsigned short*)(base + 8388608); //  4.19 MB
    unsigned short* ctxB   = (unsigned short*)(base + 12582912);//  4.19 MB
    unsigned short* actC   = (unsigned short*)(base);           //  4.19 MB alias
    unsigned short* x2B    = (unsigned short*)(base + 29360128);//  4.19 MB
    unsigned short* sactB  = (unsigned short*)(base + 33554432);//  2.10 MB
    float*          comb   = (float*)(base + 35651584);         //  0.07 MB
    float*          part   = (float*)(base + 35717120);         // 33.55 MB
    unsigned short* Wbuf   = (unsigned short*)(base + 69271552);// 67.11 MB
    int*            lists  = (int*)(base + 139526144);
    int*            cnts   = (int*)(base + 139591680);
    int*            slots  = (int*)(base + 139591936);
    int*            bases  = (int*)(base + 139657472);

    unsigned short* Qb = (unsigned short*)(base + 35717120 + 25165824);  // 4 MB
    unsigned short* Kb = Qb + (size_t)NQH * TT * HEADD;                  // 1 MB
    unsigned short* Vb = Kb + (size_t)NKVH * TT * HEADD;                 // 1 MB
    unsigned short* Vt = Vb + (size_t)NKVH * TT * HEADD;                 // 1 MB

    dim3 blk(256);

    // 1. resid = hidden + residual ; x = rmsnorm -> bf16
    add_rmsnorm_kernel<<<dim3(T), blk, 0, stream>>>(
        hidden, residual, rms1_w, residF, xB);

    // 2. qkv = x @ w_qkv   (split-K x2; reduce fused into rope_pack)
    transpose_convert<<<dim3(QKVN / 32, HD / 64), blk, 0, stream>>>(
        w_qkv, Wbuf, HD, QKVN, 0, 0);
    gemm_splitk<<<dim3(QKVN / 128, T / 128, 2), blk, 0, stream>>>(
        xB, Wbuf, part, T, QKVN, 1024, HD, HD);

    // 3. RoPE + fused 2-partial reduce + pack head-major bf16 ; V transpose
    rope_pack<<<dim3(T), blk, 0, stream>>>(
        part, part + (size_t)T * QKVN, pos_ids, Qb, Kb, Vb);
    transpose_v<<<dim3(T / 32, HEADD / 32, NKVH), blk, 0, stream>>>(Vb, Vt);

    // 4. MFMA flash attention v2 -> ctx (bf16)
    flash_attn_mfma<<<dim3(NQH, 8, 2), dim3(128), 0, stream>>>(Qb, Kb, Vt, ctxB);

    // 5+6. resid2 = ctx @ w_dense + resid ; x2 = rmsnorm  (fused reduce)
    transpose_convert<<<dim3(HD / 32, HD / 64), blk, 0, stream>>>(
        w_dense, Wbuf, HD, HD, 0, 0);
    gemm_splitk<<<dim3(HD / 128, T / 128, 4), blk, 0, stream>>>(
        ctxB, Wbuf, part, T, HD, 512, HD, HD);
    reduce4_add_rmsnorm<<<dim3(T), blk, 0, stream>>>(
        part, residF, rms2_w, out1, x2B);

    // 7. fused router -> comb ; 8. expert token lists + slots + bases
    router_fused<<<dim3(T), blk, 0, stream>>>(out1, rms2_w, gate_w, comb);
    build_lists<<<dim3(NEXP), blk, 0, stream>>>(comb, lists, slots, cnts);
    scan_cnts<<<dim3(1), dim3(64), 0, stream>>>(cnts, bases);

    // 9. shared gu = x2 @ sw13  (split-K x4) -> part
    transpose_convert<<<dim3(2 * SSI / 32, HD / 64), blk, 0, stream>>>(
        sw13, Wbuf, HD, 2 * SSI, 0, 0);
    gemm_splitk<<<dim3(HD / 128, T / 128, 4), blk, 0, stream>>>(
        x2B, Wbuf, part, T, 2 * SSI, 512, HD, HD);

    // 10. fused reduce + SwiGLU -> sactB (bf16)
    reduce_swiglu<<<dim3(T * SSI / 4 / 256), blk, 0, stream>>>(part, 4, sactB);

    // 11. out0 = shared_act @ sw2  (split-K x4)
    transpose_convert<<<dim3(HD / 32, SSI / 64), blk, 0, stream>>>(
        sw2, Wbuf, SSI, HD, 0, 0);
    gemm_splitk<<<dim3(HD / 128, T / 128, 4), blk, 0, stream>>>(
        sactB, Wbuf, part, T, HD, 256, SSI, SSI);
    reduce_partials<<<dim3(1024), blk, 0, stream>>>(
        part, 4, T * HD / 4, nullptr, out0, 0);

    // 12. sparse expert up DIRECT from f32 w13 (no transpose pass)
    moe_up_f32<<<dim3(EI / 64, 16, NEXP), blk, 0, stream>>>(
        x2B, w13, comb, lists, cnts, bases, actC);

    // 13. sparse down: actC @ w2T-slices -> 4 slot partials ; out0 += sum
    transpose_convert<<<dim3(HD / 32, (NEXP * EI) / 64), blk, 0, stream>>>(
        w2, Wbuf, NEXP * EI, HD, 0, 0);
    moe_down_gather<<<dim3(HD / 128, 16, NEXP), blk, 0, stream>>>(
        actC, Wbuf, lists, slots, cnts, bases, part);
    reduce_partials<<<dim3(1024), blk, 0, stream>>>(
        part, 4, T * HD / 4, nullptr, out0, 1);
}

// Round 15
// 349.791 us; speedup vs baseline: 1.0920x; 1.0920x over previous
//
#include <hip/hip_runtime.h>
#include <math.h>

// ---------------------------------------------------------------------------
// Problem constants
// ---------------------------------------------------------------------------
#define HD 2048      // hidden size h
#define NQH 16       // num q heads
#define NKVH 4       // num kv heads
#define HEADD 128    // head dim
#define QKVN 3072    // qkv cols
#define NEXP 16      // experts
#define EI 512       // expert intermediate
#define SSI 1024     // shared intermediate
#define TOPK 4
#define TT 1024      // tokens

typedef __bf16 bf16x8 __attribute__((ext_vector_type(8)));
typedef float f32x4 __attribute__((ext_vector_type(4)));
typedef unsigned short u16x8 __attribute__((ext_vector_type(8)));

static __device__ __forceinline__ unsigned short f2bf(float f) {
    union { float f; unsigned int u; } v; v.f = f;
    unsigned int r = v.u + 0x7fff + ((v.u >> 16) & 1);
    return (unsigned short)(r >> 16);
}

static __device__ __forceinline__ void gl_lds16(const unsigned short* g,
                                                unsigned short* l) {
    __builtin_amdgcn_global_load_lds(
        (const __attribute__((address_space(1))) unsigned int*)g,
        (__attribute__((address_space(3))) unsigned int*)l, 16, 0, 0);
}

// ---------------------------------------------------------------------------
// Fused add + RMSNorm. resid_out(f32 opt) ; x_bf (bf16)
// ---------------------------------------------------------------------------
__global__ __launch_bounds__(256) void add_rmsnorm_kernel(
    const float* __restrict__ a, const float* __restrict__ b,
    const float* __restrict__ w, float* __restrict__ resid_out,
    unsigned short* __restrict__ x_bf)
{
    int t = blockIdx.x;
    int tid = threadIdx.x;
    const float4* a4 = (const float4*)(a + (size_t)t * HD);
    const float4* b4 = b ? (const float4*)(b + (size_t)t * HD) : nullptr;
    float4* r4 = resid_out ? (float4*)(resid_out + (size_t)t * HD) : nullptr;
    const float4* w4 = (const float4*)w;

    float4 v[2];
    float ss = 0.f;
#pragma unroll
    for (int l = 0; l < 2; ++l) {
        int idx = tid + l * 256;
        float4 va = a4[idx];
        if (b4) {
            float4 vb = b4[idx];
            va.x += vb.x; va.y += vb.y; va.z += vb.z; va.w += vb.w;
        }
        if (r4) r4[idx] = va;
        v[l] = va;
        ss += va.x * va.x + va.y * va.y + va.z * va.z + va.w * va.w;
    }
    for (int off = 32; off > 0; off >>= 1) ss += __shfl_down(ss, off);
    __shared__ float red[4];
    int lane = tid & 63, wv = tid >> 6;
    if (lane == 0) red[wv] = ss;
    __syncthreads();
    if (tid == 0) {
        float s = red[0] + red[1] + red[2] + red[3];
        red[0] = rsqrtf(s / (float)HD + 1e-6f);
    }
    __syncthreads();
    float inv = red[0];
#pragma unroll
    for (int l = 0; l < 2; ++l) {
        int idx = tid + l * 256;
        float4 va = v[l], vw = w4[idx];
        ushort4 ob;
        ob.x = f2bf(va.x * inv * vw.x);
        ob.y = f2bf(va.y * inv * vw.y);
        ob.z = f2bf(va.z * inv * vw.z);
        ob.w = f2bf(va.w * inv * vw.w);
        ((ushort4*)(x_bf + (size_t)t * HD))[idx] = ob;
    }
}

// ---------------------------------------------------------------------------
// Fused: sum 4 split-K partials + resid -> resid2 (f32) ; rmsnorm -> x_bf
// One block per token.
// ---------------------------------------------------------------------------
__global__ __launch_bounds__(256) void reduce4_add_rmsnorm(
    const float* __restrict__ part, const float* __restrict__ resid,
    const float* __restrict__ w, float* __restrict__ resid2_out,
    unsigned short* __restrict__ x_bf)
{
    const size_t NP = (size_t)TT * HD / 4;   // float4 stride per partial
    int t = blockIdx.x;
    int tid = threadIdx.x;
    const float4* p4 = (const float4*)part;
    const float4* r4 = (const float4*)(resid + (size_t)t * HD);
    float4* o4 = (float4*)(resid2_out + (size_t)t * HD);
    const float4* w4 = (const float4*)w;

    float4 v[2];
    float ss = 0.f;
#pragma unroll
    for (int l = 0; l < 2; ++l) {
        int li = tid + l * 256;
        size_t idx = (size_t)t * (HD / 4) + li;
        float4 s = p4[idx];
        float4 q1 = p4[NP + idx], q2 = p4[2 * NP + idx], q3 = p4[3 * NP + idx];
        float4 rr = r4[li];
        s.x += q1.x + q2.x + q3.x + rr.x;
        s.y += q1.y + q2.y + q3.y + rr.y;
        s.z += q1.z + q2.z + q3.z + rr.z;
        s.w += q1.w + q2.w + q3.w + rr.w;
        o4[li] = s;
        v[l] = s;
        ss += s.x * s.x + s.y * s.y + s.z * s.z + s.w * s.w;
    }
    for (int off = 32; off > 0; off >>= 1) ss += __shfl_down(ss, off);
    __shared__ float red[4];
    int lane = tid & 63, wv = tid >> 6;
    if (lane == 0) red[wv] = ss;
    __syncthreads();
    if (tid == 0) {
        float s = red[0] + red[1] + red[2] + red[3];
        red[0] = rsqrtf(s / (float)HD + 1e-6f);
    }
    __syncthreads();
    float inv = red[0];
#pragma unroll
    for (int l = 0; l < 2; ++l) {
        int li = tid + l * 256;
        float4 va = v[l], vw = w4[li];
        ushort4 ob;
        ob.x = f2bf(va.x * inv * vw.x);
        ob.y = f2bf(va.y * inv * vw.y);
        ob.z = f2bf(va.z * inv * vw.z);
        ob.w = f2bf(va.w * inv * vw.w);
        ((ushort4*)(x_bf + (size_t)t * HD))[li] = ob;
    }
}

// ---------------------------------------------------------------------------
// Transpose + convert v2: f32 in [K][N] -> bf16 out [N][K]  (per-z strides)
// 64k x 32n tiles; reads 128B/row, writes 128B/row.  grid (N/32, K/64, z)
// ---------------------------------------------------------------------------
__global__ __launch_bounds__(256) void transpose_convert(
    const float* __restrict__ in, unsigned short* __restrict__ out,
    int K, int N, long long strideIn, long long strideOut)
{
    __shared__ float tile[64][33];
    const int n0 = blockIdx.x * 32;
    const int k0 = blockIdx.y * 64;
    const float* ip = in + (size_t)blockIdx.z * strideIn;
    unsigned short* op = out + (size_t)blockIdx.z * strideOut;
    int tid = threadIdx.x;
    int c = (tid & 7) * 4;
#pragma unroll
    for (int i = 0; i < 2; ++i) {
        int r = (tid >> 3) + i * 32;
        float4 v = *(const float4*)(ip + (size_t)(k0 + r) * N + n0 + c);
        tile[r][c] = v.x; tile[r][c + 1] = v.y;
        tile[r][c + 2] = v.z; tile[r][c + 3] = v.w;
    }
    __syncthreads();
    int rr = tid >> 3;
    int kc = (tid & 7) * 8;
    u16x8 o;
#pragma unroll
    for (int j = 0; j < 8; ++j) o[j] = f2bf(tile[kc + j][rr]);
    *(u16x8*)(op + (size_t)(n0 + rr) * K + k0 + kc) = o;
}

// ---------------------------------------------------------------------------
// Split-K bf16 MFMA GEMM, STAGE-early double-buffered, BK=64,
// T4 counted-vmcnt (8 loads/stage stay in flight across raw barriers).
// ---------------------------------------------------------------------------
#define SBK 64

__global__ __launch_bounds__(256) void gemm_splitk(
    const unsigned short* __restrict__ A, const unsigned short* __restrict__ B,
    float* __restrict__ Cpart, int M, int N, int Kc, int ldA, int ldB)
{
    __shared__ unsigned short As[2][128 * SBK];
    __shared__ unsigned short Bs[2][128 * SBK];

    const int tid = threadIdx.x;
    const int wave = tid >> 6;
    const int lane = tid & 63;
    const int wr = wave >> 1, wc = wave & 1;
    const int l15 = lane & 15;
    const int row0 = blockIdx.y * 128;
    const int col0 = blockIdx.x * 128;
    const int z = blockIdx.z;

    const unsigned short* Ap = A + (size_t)row0 * ldA + (size_t)z * Kc;
    const unsigned short* Bp = B + (size_t)col0 * ldB + (size_t)z * Kc;

    const int r_st = tid >> 3;
    const int q_st = tid & 7;
    const int csrc = (q_st ^ (r_st & 7)) << 3;

    f32x4 acc[4][4] = {};

    const int nsteps = Kc / SBK;

#define STAGE_SK(buf, k0s)                                                    \
    {                                                                         \
        _Pragma("unroll")                                                     \
        for (int i = 0; i < 4; ++i) {                                         \
            int rr = r_st + i * 32;                                           \
            gl_lds16(Ap + (size_t)rr * ldA + (k0s) + csrc,                    \
                     &As[buf][rr * SBK + q_st * 8]);                          \
            gl_lds16(Bp + (size_t)rr * ldB + (k0s) + csrc,                    \
                     &Bs[buf][rr * SBK + q_st * 8]);                          \
        }                                                                     \
    }

    STAGE_SK(0, 0);

    for (int s = 0; s < nsteps; ++s) {
        const int cur = s & 1;
        if (s + 1 < nsteps) {
            STAGE_SK(cur ^ 1, (s + 1) * SBK);
            asm volatile("s_waitcnt vmcnt(8)" ::: "memory");
        } else {
            asm volatile("s_waitcnt vmcnt(0)" ::: "memory");
        }
        __builtin_amdgcn_s_barrier();

#pragma unroll
        for (int half = 0; half < 2; ++half) {
            const int q = half * 4 + (lane >> 4);
            bf16x8 af[4], bfv[4];
#pragma unroll
            for (int i = 0; i < 4; ++i) {
                int R = wr * 64 + i * 16 + l15;
                af[i] = *(const bf16x8*)&As[cur][R * SBK + ((q ^ (R & 7)) << 3)];
            }
#pragma unroll
            for (int j = 0; j < 4; ++j) {
                int R = wc * 64 + j * 16 + l15;
                bfv[j] = *(const bf16x8*)&Bs[cur][R * SBK + ((q ^ (R & 7)) << 3)];
            }
#pragma unroll
            for (int mi = 0; mi < 4; ++mi)
#pragma unroll
                for (int nj = 0; nj < 4; ++nj)
                    acc[mi][nj] = __builtin_amdgcn_mfma_f32_16x16x32_bf16(
                        af[mi], bfv[nj], acc[mi][nj], 0, 0, 0);
        }
        __builtin_amdgcn_s_barrier();
    }

    float* Cp = Cpart + (size_t)z * M * N;
#pragma unroll
    for (int mi = 0; mi < 4; ++mi)
#pragma unroll
        for (int nj = 0; nj < 4; ++nj)
#pragma unroll
            for (int r = 0; r < 4; ++r) {
                int row = row0 + wr * 64 + mi * 16 + (lane >> 4) * 4 + r;
                int col = col0 + wc * 64 + nj * 16 + l15;
                Cp[(size_t)row * N + col] = acc[mi][nj][r];
            }
}

// ---------------------------------------------------------------------------
// Reduce split-K partials: out = sum_z part[z] (+ add) (+= out if acc)
// ---------------------------------------------------------------------------
__global__ __launch_bounds__(256) void reduce_partials(
    const float* __restrict__ part, int ns, int n4,
    const float* __restrict__ add, float* __restrict__ out, int acc)
{
    const float4* p4 = (const float4*)part;
    const float4* a4 = (const float4*)add;
    float4* o4 = (float4*)out;
    for (int idx = blockIdx.x * 256 + threadIdx.x; idx < n4;
         idx += gridDim.x * 256) {
        float4 s = p4[idx];
        for (int z = 1; z < ns; ++z) {
            float4 q = p4[(size_t)z * n4 + idx];
            s.x += q.x; s.y += q.y; s.z += q.z; s.w += q.w;
        }
        if (add) {
            float4 q = a4[idx];
            s.x += q.x; s.y += q.y; s.z += q.z; s.w += q.w;
        }
        if (acc) {
            float4 q = o4[idx];
            s.x += q.x; s.y += q.y; s.z += q.z; s.w += q.w;
        }
        o4[idx] = s;
    }
}

// ---------------------------------------------------------------------------
// Reduce split-K partials of shared-expert gu [T][2048] + SwiGLU -> bf16
// ---------------------------------------------------------------------------
__global__ __launch_bounds__(256) void reduce_swiglu(
    const float* __restrict__ part, int ns, unsigned short* __restrict__ out)
{
    int idx4 = blockIdx.x * 256 + threadIdx.x;
    int t = idx4 >> 8;
    int i4 = (idx4 & 255) * 4;
    const float4* pg = (const float4*)(part + (size_t)t * (2 * SSI) + i4);
    const float4* pu = (const float4*)(part + (size_t)t * (2 * SSI) + SSI + i4);
    float4 g = pg[0], u = pu[0];
    for (int z = 1; z < ns; ++z) {
        float4 g2 = *(const float4*)((const float*)pg + (size_t)z * TT * 2 * SSI);
        float4 u2 = *(const float4*)((const float*)pu + (size_t)z * TT * 2 * SSI);
        g.x += g2.x; g.y += g2.y; g.z += g2.z; g.w += g2.w;
        u.x += u2.x; u.y += u2.y; u.z += u2.z; u.w += u2.w;
    }
    ushort4 o;
    o.x = f2bf((g.x / (1.f + __expf(-g.x))) * u.x);
    o.y = f2bf((g.y / (1.f + __expf(-g.y))) * u.y);
    o.z = f2bf((g.z / (1.f + __expf(-g.z))) * u.z);
    o.w = f2bf((g.w / (1.f + __expf(-g.w))) * u.w);
    *(ushort4*)(out + (size_t)t * SSI + i4) = o;
}

// ---------------------------------------------------------------------------
// Build per-expert token lists + slot ranks (token-ordered, deterministic).
// ---------------------------------------------------------------------------
__global__ __launch_bounds__(256) void build_lists(
    const float* __restrict__ comb, int* __restrict__ lists,
    int* __restrict__ slots, int* __restrict__ cnts)
{
    int e = blockIdx.x;
    int tid = threadIdx.x;
    __shared__ int sc[256];
    int loc[4];
    int c = 0;
#pragma unroll
    for (int j = 0; j < 4; ++j) {
        int t = tid * 4 + j;
        if (comb[(size_t)t * NEXP + e] > 0.f) loc[c++] = t;
    }
    sc[tid] = c;
    __syncthreads();
    for (int off = 1; off < 256; off <<= 1) {
        int v = (tid >= off) ? sc[tid - off] : 0;
        __syncthreads();
        sc[tid] += v;
        __syncthreads();
    }
    int base = sc[tid] - c;
    for (int i = 0; i < c; ++i) {
        int t = loc[i];
        int s = 0;
        for (int e2 = 0; e2 < e; ++e2)
            s += (comb[(size_t)t * NEXP + e2] > 0.f) ? 1 : 0;
        lists[e * TT + base + i] = t;
        slots[e * TT + base + i] = s;
    }
    if (tid == 255) cnts[e] = sc[255];
}

// ---------------------------------------------------------------------------
// Prefix-scan expert counts -> bases[17]
// ---------------------------------------------------------------------------
__global__ void scan_cnts(const int* __restrict__ cnts, int* __restrict__ bases)
{
    if (threadIdx.x == 0 && blockIdx.x == 0) {
        int a = 0;
        for (int e = 0; e < NEXP; ++e) { bases[e] = a; a += cnts[e]; }
        bases[NEXP] = a;
    }
}

// ---------------------------------------------------------------------------
// Sparse MoE expert-up + fused SwiGLU*comb -> compact ragged actC (bf16).
// 2-buffer T4 counted-vmcnt (6 loads/stage in flight), 48 KB LDS.
// ---------------------------------------------------------------------------
__global__ __launch_bounds__(256) void moe_up_gather(
    const unsigned short* __restrict__ x2B,
    const unsigned short* __restrict__ w13T,
    const float* __restrict__ comb,
    const int* __restrict__ lists,
    const int* __restrict__ cnts,
    const int* __restrict__ bases,
    unsigned short* __restrict__ actC)
{
    __shared__ unsigned short As[2][64 * 64];
    __shared__ unsigned short Bgs[2][64 * 64];
    __shared__ unsigned short Bus[2][64 * 64];

    const int e = blockIdx.z;
    const int cnt = cnts[e];
    const int m0 = blockIdx.y * 64;
    if (m0 >= cnt) return;
    const int n0 = blockIdx.x * 64;
    const int base_e = bases[e];

    const int tid = threadIdx.x;
    const int w = tid >> 6;
    const int lane = tid & 63;
    const int l15 = lane & 15;
    const int g = lane >> 4;

    const int r0 = tid >> 3;          // 0..31
    const int q_st = tid & 7;
    const int swz = (q_st ^ (r0 & 7)) << 3;

    int a0 = m0 + r0, a1 = m0 + r0 + 32;
    int tok0 = lists[e * TT + (a0 < cnt ? a0 : cnt - 1)];
    int tok1 = lists[e * TT + (a1 < cnt ? a1 : cnt - 1)];
    const unsigned short* Asrc0 = x2B + (size_t)tok0 * HD;
    const unsigned short* Asrc1 = x2B + (size_t)tok1 * HD;
    const unsigned short* Bbase = w13T + (size_t)e * 1024 * HD;
    const unsigned short* Bg0 = Bbase + (size_t)(n0 + r0) * HD;
    const unsigned short* Bg1 = Bbase + (size_t)(n0 + r0 + 32) * HD;
    const unsigned short* Bu0 = Bg0 + (size_t)512 * HD;
    const unsigned short* Bu1 = Bg1 + (size_t)512 * HD;

    f32x4 ag[4] = {};
    f32x4 au[4] = {};

#define STAGE_UP(buf, k0s)                                                    \
    {                                                                         \
        gl_lds16(Asrc0 + (k0s) + swz, &As[buf][(tid) * 8]);                   \
        gl_lds16(Asrc1 + (k0s) + swz, &As[buf][(tid + 256) * 8]);             \
        gl_lds16(Bg0 + (k0s) + swz, &Bgs[buf][(tid) * 8]);                    \
        gl_lds16(Bg1 + (k0s) + swz, &Bgs[buf][(tid + 256) * 8]);              \
        gl_lds16(Bu0 + (k0s) + swz, &Bus[buf][(tid) * 8]);                    \
        gl_lds16(Bu1 + (k0s) + swz, &Bus[buf][(tid + 256) * 8]);              \
    }

    STAGE_UP(0, 0);

    const int nsteps = HD / 64;
    for (int s = 0; s < nsteps; ++s) {
        const int cur = s & 1;
        if (s + 1 < nsteps) {
            STAGE_UP(cur ^ 1, (s + 1) * 64);
            asm volatile("s_waitcnt vmcnt(6)" ::: "memory");
        } else {
            asm volatile("s_waitcnt vmcnt(0)" ::: "memory");
        }
        __builtin_amdgcn_s_barrier();

#pragma unroll
        for (int kk2 = 0; kk2 < 2; ++kk2) {
            const int q = kk2 * 4 + g;
            bf16x8 af[4], bg, bu;
#pragma unroll
            for (int i = 0; i < 4; ++i) {
                int R = i * 16 + l15;
                af[i] = *(const bf16x8*)&As[cur][R * 64 + ((q ^ (R & 7)) << 3)];
            }
            {
                int R = w * 16 + l15;
                int off = R * 64 + ((q ^ (R & 7)) << 3);
                bg = *(const bf16x8*)&Bgs[cur][off];
                bu = *(const bf16x8*)&Bus[cur][off];
            }
#pragma unroll
            for (int mi = 0; mi < 4; ++mi) {
                ag[mi] = __builtin_amdgcn_mfma_f32_16x16x32_bf16(
                    af[mi], bg, ag[mi], 0, 0, 0);
                au[mi] = __builtin_amdgcn_mfma_f32_16x16x32_bf16(
                    af[mi], bu, au[mi], 0, 0, 0);
            }
        }
        __builtin_amdgcn_s_barrier();
    }

#pragma unroll
    for (int mi = 0; mi < 4; ++mi) {
#pragma unroll
        for (int r = 0; r < 4; ++r) {
            int grow = m0 + mi * 16 + g * 4 + r;
            if (grow >= cnt) continue;
            int tok = lists[e * TT + grow];
            float cw = comb[(size_t)tok * NEXP + e];
            int col = n0 + w * 16 + l15;
            float gg = ag[mi][r];
            float uu = au[mi][r];
            float v = (gg / (1.f + __expf(-gg))) * uu * cw;
            actC[(size_t)(base_e + grow) * EI + col] = f2bf(v);
        }
    }
}

// ---------------------------------------------------------------------------
// Sparse MoE down: actC @ w2T-slice -> slot partials (f32).
// 2-buffer T4 counted-vmcnt (6 loads/stage in flight), 48 KB LDS.
// ---------------------------------------------------------------------------
__global__ __launch_bounds__(256) void moe_down_gather(
    const unsigned short* __restrict__ actC,
    const unsigned short* __restrict__ w2T,   // [HD][NEXP*EI]
    const int* __restrict__ lists,
    const int* __restrict__ slots,
    const int* __restrict__ cnts,
    const int* __restrict__ bases,
    float* __restrict__ slotpart)
{
    __shared__ unsigned short As[2][64 * 64];
    __shared__ unsigned short Bs[2][128 * 64];

    const int e = blockIdx.z;
    const int cnt = cnts[e];
    const int m0 = blockIdx.y * 64;
    if (m0 >= cnt) return;
    const int n0 = blockIdx.x * 128;
    const int base_e = bases[e];

    const int tid = threadIdx.x;
    const int w = tid >> 6;
    const int lane = tid & 63;
    const int l15 = lane & 15;
    const int g = lane >> 4;

    const int r0 = tid >> 3;          // 0..31
    const int q_st = tid & 7;
    const int swz = (q_st ^ (r0 & 7)) << 3;

    int a0 = m0 + r0, a1 = m0 + r0 + 32;
    const unsigned short* Asrc0 =
        actC + (size_t)(base_e + (a0 < cnt ? a0 : cnt - 1)) * EI;
    const unsigned short* Asrc1 =
        actC + (size_t)(base_e + (a1 < cnt ? a1 : cnt - 1)) * EI;
    const unsigned short* Bbase = w2T + (size_t)e * EI;

#define STAGE_DN(buf, k0s)                                                    \
    {                                                                         \
        gl_lds16(Asrc0 + (k0s) + swz, &As[buf][(tid) * 8]);                   \
        gl_lds16(Asrc1 + (k0s) + swz, &As[buf][(tid + 256) * 8]);             \
        _Pragma("unroll")                                                     \
        for (int i = 0; i < 4; ++i) {                                         \
            int rr = r0 + i * 32;                                             \
            gl_lds16(Bbase + (size_t)(n0 + rr) * (NEXP * EI) + (k0s) + swz,   \
                     &Bs[buf][(tid + i * 256) * 8]);                          \
        }                                                                     \
    }

    f32x4 acc[4][2] = {};

    STAGE_DN(0, 0);

    const int nsteps = EI / 64;
    for (int s = 0; s < nsteps; ++s) {
        const int cur = s & 1;
        if (s + 1 < nsteps) {
            STAGE_DN(cur ^ 1, (s + 1) * 64);
            asm volatile("s_waitcnt vmcnt(6)" ::: "memory");
        } else {
            asm volatile("s_waitcnt vmcnt(0)" ::: "memory");
        }
        __builtin_amdgcn_s_barrier();

#pragma unroll
        for (int kk2 = 0; kk2 < 2; ++kk2) {
            const int q = kk2 * 4 + g;
            bf16x8 af[4], bf[2];
#pragma unroll
            for (int i = 0; i < 4; ++i) {
                int R = i * 16 + l15;
                af[i] = *(const bf16x8*)&As[cur][R * 64 + ((q ^ (R & 7)) << 3)];
            }
#pragma unroll
            for (int j = 0; j < 2; ++j) {
                int R = w * 32 + j * 16 + l15;
                bf[j] = *(const bf16x8*)&Bs[cur][R * 64 + ((q ^ (R & 7)) << 3)];
            }
#pragma unroll
            for (int mi = 0; mi < 4; ++mi)
#pragma unroll
                for (int nj = 0; nj < 2; ++nj)
                    acc[mi][nj] = __builtin_amdgcn_mfma_f32_16x16x32_bf16(
                        af[mi], bf[nj], acc[mi][nj], 0, 0, 0);
        }
        __builtin_amdgcn_s_barrier();
    }

#pragma unroll
    for (int mi = 0; mi < 4; ++mi) {
#pragma unroll
        for (int r = 0; r < 4; ++r) {
            int grow = m0 + mi * 16 + g * 4 + r;
            if (grow >= cnt) continue;
            int tok = lists[e * TT + grow];
            int sl  = slots[e * TT + grow];
            float* orow = slotpart + (size_t)sl * TT * HD + (size_t)tok * HD;
#pragma unroll
            for (int nj = 0; nj < 2; ++nj) {
                int col = n0 + w * 32 + nj * 16 + l15;
                orow[col] = acc[mi][nj][r];
            }
        }
    }
}

// ---------------------------------------------------------------------------
// RoPE + pack to head-major bf16, fused qkv split-K reduce (2 partials).
// ---------------------------------------------------------------------------
__global__ __launch_bounds__(256) void rope_pack(
    const float* __restrict__ qkv0, const float* __restrict__ qkv1,
    const int* __restrict__ pos_ids,
    unsigned short* __restrict__ Qb, unsigned short* __restrict__ Kb,
    unsigned short* __restrict__ Vb)
{
    const float SCALE = 0.08838834764831843f;
    int t = blockIdx.x;
    int tid = threadIdx.x;
    int w = tid >> 6, lane = tid & 63;
    float pos = (float)pos_ids[t];
    float invf = powf(10000.0f, -(float)lane * (1.0f / 64.0f));
    float ang = pos * invf;
    float c = cosf(ang);
    float s = sinf(ang);
    const float* row0 = qkv0 + (size_t)t * QKVN;
    const float* row1 = qkv1 + (size_t)t * QKVN;
#pragma unroll
    for (int j = 0; j < 5; ++j) {
        int hh = w * 5 + j;
        const float* hb0 = row0 + hh * HEADD;
        const float* hb1 = row1 + hh * HEADD;
        float x1 = hb0[lane] + hb1[lane];
        float x2 = hb0[lane + 64] + hb1[lane + 64];
        float o1 = x1 * c - x2 * s;
        float o2 = x2 * c + x1 * s;
        if (hh < NQH) {
            unsigned short* qp = Qb + ((size_t)hh * TT + t) * HEADD;
            qp[lane] = f2bf(o1 * SCALE);
            qp[lane + 64] = f2bf(o2 * SCALE);
        } else {
            unsigned short* kp = Kb + ((size_t)(hh - NQH) * TT + t) * HEADD;
            kp[lane] = f2bf(o1);
            kp[lane + 64] = f2bf(o2);
        }
    }
    float2 v0 = *(const float2*)(row0 + 2560 + tid * 2);
    float2 v1 = *(const float2*)(row1 + 2560 + tid * 2);
    int kvh = tid >> 6;
    int d = (tid * 2) & 127;
    unsigned int packed = (unsigned int)f2bf(v0.x + v1.x) |
                          ((unsigned int)f2bf(v0.y + v1.y) << 16);
    *(unsigned int*)(Vb + ((size_t)kvh * TT + t) * HEADD + d) = packed;
}

// ---------------------------------------------------------------------------
// V transpose: Vb[kvh][t][128] -> Vt[kvh][128][t]
// ---------------------------------------------------------------------------
__global__ __launch_bounds__(256) void transpose_v(
    const unsigned short* __restrict__ Vb, unsigned short* __restrict__ Vt)
{
    __shared__ unsigned short tile[32][40];
    const int kvh = blockIdx.z;
    const int t0 = blockIdx.x * 32, d0 = blockIdx.y * 32;
    int tid = threadIdx.x;
    int r = tid >> 3, c4 = (tid & 7) * 4;
    ushort4 v = *(const ushort4*)(Vb + ((size_t)kvh * TT + t0 + r) * HEADD + d0 + c4);
    tile[r][c4] = v.x; tile[r][c4 + 1] = v.y;
    tile[r][c4 + 2] = v.z; tile[r][c4 + 3] = v.w;
    __syncthreads();
    ushort4 o;
    o.x = tile[c4 + 0][r];
    o.y = tile[c4 + 1][r];
    o.z = tile[c4 + 2][r];
    o.w = tile[c4 + 3][r];
    *(ushort4*)(Vt + ((size_t)kvh * HEADD + d0 + r) * TT + t0 + c4) = o;
}

// ---------------------------------------------------------------------------
// MFMA flash attention v2 — LDS-staged K/V, double-buffered, triangle-paired,
// T4 counted-vmcnt (16 loads/stage in flight across raw barriers).
// ---------------------------------------------------------------------------
__global__ __launch_bounds__(128) void flash_attn_mfma(
    const unsigned short* __restrict__ Qb,
    const unsigned short* __restrict__ Kb,
    const unsigned short* __restrict__ Vt,
    unsigned short* __restrict__ ctx)
{
    __shared__ __align__(16) unsigned short Ks[2][64 * 128];
    __shared__ __align__(16) unsigned short Vs[2][128 * 64];
    __shared__ __align__(16) unsigned short Pl[2][16][72];

    const int h   = blockIdx.x;
    const int p   = blockIdx.y;
    const int rh  = blockIdx.z;
    const int kvh = h >> 2;
    const int tid = threadIdx.x;
    const int w   = tid >> 6;
    const int lane = tid & 63;
    const int l15 = lane & 15;
    const int g   = lane >> 4;

    const unsigned short* Kh = Kb + (size_t)kvh * TT * HEADD;
    const unsigned short* Vh = Vt + (size_t)kvh * HEADD * TT;

#define STAGE_KV(buf, s0s)                                                    \
    {                                                                         \
        _Pragma("unroll")                                                     \
        for (int i = 0; i < 8; ++i) {                                         \
            int idx = tid + i * 128;                                          \
            int r = idx >> 4, c = idx & 15;                                   \
            int csw = (c & 8) | ((c ^ r) & 7);                                \
            gl_lds16(Kh + (size_t)((s0s) + r) * HEADD + csw * 8,              \
                     &Ks[buf][idx * 8]);                                      \
        }                                                                     \
        _Pragma("unroll")                                                     \
        for (int i = 0; i < 8; ++i) {                                         \
            int idx = tid + i * 128;                                          \
            int r = idx >> 3, c = idx & 7;                                    \
            int csw = (c ^ r) & 7;                                            \
            gl_lds16(Vh + (size_t)r * TT + (s0s) + csw * 8,                   \
                     &Vs[buf][idx * 8]);                                      \
        }                                                                     \
    }

    const int qts[2] = {p, 15 - p};

#pragma unroll
    for (int qi = 0; qi < 2; ++qi) {
        const int qt = qts[qi];
        const int q0 = qt * 64 + rh * 32 + w * 16;
        const int ntiles = qt + 1;

        const unsigned short* Qrow = Qb + ((size_t)h * TT + q0 + l15) * HEADD;
        bf16x8 qf[4];
#pragma unroll
        for (int kk = 0; kk < 4; ++kk)
            qf[kk] = *(const bf16x8*)(Qrow + kk * 32 + g * 8);

        float m_i[4], l_i[4];
#pragma unroll
        for (int r = 0; r < 4; ++r) { m_i[r] = -1e30f; l_i[r] = 0.f; }
        f32x4 of[8] = {};

        STAGE_KV(0, 0);

        for (int st = 0; st < ntiles; ++st) {
            const int cur = st & 1;
            const int s0 = st * 64;
            if (st + 1 < ntiles) {
                STAGE_KV(cur ^ 1, (st + 1) * 64);
                asm volatile("s_waitcnt vmcnt(16)" ::: "memory");
            } else {
                asm volatile("s_waitcnt vmcnt(0)" ::: "memory");
            }
            __builtin_amdgcn_s_barrier();

            f32x4 sacc[4] = {};
#pragma unroll
            for (int kk = 0; kk < 4; ++kk) {
#pragma unroll
                for (int n = 0; n < 4; ++n) {
                    int R = n * 16 + l15;
                    int cidx = kk * 4 + g;
                    int cs = (cidx & 8) | ((cidx ^ R) & 7);
                    bf16x8 kb = *(const bf16x8*)&Ks[cur][R * 128 + cs * 8];
                    sacc[n] = __builtin_amdgcn_mfma_f32_16x16x32_bf16(
                        qf[kk], kb, sacc[n], 0, 0, 0);
                }
            }

            const bool diag = (st == qt);
            float alpha[4];
#pragma unroll
            for (int r = 0; r < 4; ++r) {
                const int qrow = q0 + g * 4 + r;
                float sv[4] = {sacc[0][r], sacc[1][r], sacc[2][r], sacc[3][r]};
                if (diag) {
#pragma unroll
                    for (int n = 0; n < 4; ++n)
                        if (s0 + n * 16 + l15 > qrow) sv[n] = -1e30f;
                }
                float rm = fmaxf(fmaxf(sv[0], sv[1]), fmaxf(sv[2], sv[3]));
                rm = fmaxf(rm, __shfl_xor(rm, 1));
                rm = fmaxf(rm, __shfl_xor(rm, 2));
                rm = fmaxf(rm, __shfl_xor(rm, 4));
                rm = fmaxf(rm, __shfl_xor(rm, 8));
                float mnew = fmaxf(m_i[r], rm);
                alpha[r] = __expf(m_i[r] - mnew);
                float p0 = __expf(sv[0] - mnew);
                float p1 = __expf(sv[1] - mnew);
                float p2 = __expf(sv[2] - mnew);
                float p3 = __expf(sv[3] - mnew);
                float rs = p0 + p1 + p2 + p3;
                rs += __shfl_xor(rs, 1);
                rs += __shfl_xor(rs, 2);
                rs += __shfl_xor(rs, 4);
                rs += __shfl_xor(rs, 8);
                l_i[r] = l_i[r] * alpha[r] + rs;
                m_i[r] = mnew;
                Pl[w][g * 4 + r][0 * 16 + l15] = f2bf(p0);
                Pl[w][g * 4 + r][1 * 16 + l15] = f2bf(p1);
                Pl[w][g * 4 + r][2 * 16 + l15] = f2bf(p2);
                Pl[w][g * 4 + r][3 * 16 + l15] = f2bf(p3);
            }

#pragma unroll
            for (int nd = 0; nd < 8; ++nd)
#pragma unroll
                for (int r = 0; r < 4; ++r)
                    of[nd][r] *= alpha[r];

#pragma unroll
            for (int kk2 = 0; kk2 < 2; ++kk2) {
                bf16x8 pa = *(const bf16x8*)&Pl[w][l15][kk2 * 32 + g * 8];
#pragma unroll
                for (int nd = 0; nd < 8; ++nd) {
                    int R = nd * 16 + l15;
                    int cidx = kk2 * 4 + g;
                    int cs = (cidx ^ R) & 7;
                    bf16x8 vb = *(const bf16x8*)&Vs[cur][R * 64 + cs * 8];
                    of[nd] = __builtin_amdgcn_mfma_f32_16x16x32_bf16(
                        pa, vb, of[nd], 0, 0, 0);
                }
            }
            __builtin_amdgcn_s_barrier();
        }

        float invl[4];
#pragma unroll
        for (int r = 0; r < 4; ++r) invl[r] = 1.f / l_i[r];
#pragma unroll
        for (int nd = 0; nd < 8; ++nd)
#pragma unroll
            for (int r = 0; r < 4; ++r) {
                int trow = q0 + g * 4 + r;
                ctx[(size_t)trow * (NQH * HEADD) + h * HEADD + nd * 16 + l15] =
                    f2bf(of[nd][r] * invl[r]);
            }
    }
}

// ---------------------------------------------------------------------------
// Fused router: rmsnorm(resid2)*w . gate_w, softmax top-4 -> comb (T,16)
// ---------------------------------------------------------------------------
__global__ __launch_bounds__(256) void router_fused(
    const float* __restrict__ resid2, const float* __restrict__ w,
    const float* __restrict__ gate_w, float* __restrict__ comb)
{
    int t = blockIdx.x;
    int tid = threadIdx.x;
    int lane = tid & 63, wv = tid >> 6;

    const float4* r4 = (const float4*)(resid2 + (size_t)t * HD);
    float4 xa = r4[tid * 2], xb = r4[tid * 2 + 1];
    float ss = xa.x * xa.x + xa.y * xa.y + xa.z * xa.z + xa.w * xa.w +
               xb.x * xb.x + xb.y * xb.y + xb.z * xb.z + xb.w * xb.w;
    for (int off = 32; off > 0; off >>= 1) ss += __shfl_down(ss, off);
    __shared__ float red[4];
    if (lane == 0) red[wv] = ss;
    __syncthreads();
    float inv = rsqrtf((red[0] + red[1] + red[2] + red[3]) / (float)HD + 1e-6f);

    const float4* w4 = (const float4*)w;
    float4 wa = w4[tid * 2], wb = w4[tid * 2 + 1];
    float xs[8] = {xa.x * wa.x * inv, xa.y * wa.y * inv, xa.z * wa.z * inv,
                   xa.w * wa.w * inv, xb.x * wb.x * inv, xb.y * wb.y * inv,
                   xb.z * wb.z * inv, xb.w * wb.w * inv};

    float acc[16] = {};
    int kbase = tid * 8;
#pragma unroll
    for (int j = 0; j < 8; ++j) {
        float xv = xs[j];
        const float4* wrow = (const float4*)(gate_w + (size_t)(kbase + j) * NEXP);
        float4 w0 = wrow[0], w1 = wrow[1], w2 = wrow[2], w3 = wrow[3];
        acc[0] += xv * w0.x;  acc[1] += xv * w0.y;  acc[2] += xv * w0.z;  acc[3] += xv * w0.w;
        acc[4] += xv * w1.x;  acc[5] += xv * w1.y;  acc[6] += xv * w1.z;  acc[7] += xv * w1.w;
        acc[8] += xv * w2.x;  acc[9] += xv * w2.y;  acc[10] += xv * w2.z; acc[11] += xv * w2.w;
        acc[12] += xv * w3.x; acc[13] += xv * w3.y; acc[14] += xv * w3.z; acc[15] += xv * w3.w;
    }
    __shared__ float red2[4][16];
#pragma unroll
    for (int e = 0; e < 16; ++e) {
        float v = acc[e];
        v += __shfl_xor(v, 1);
        v += __shfl_xor(v, 2);
        v += __shfl_xor(v, 4);
        v += __shfl_xor(v, 8);
        v += __shfl_xor(v, 16);
        v += __shfl_xor(v, 32);
        if (lane == 0) red2[wv][e] = v;
    }
    __syncthreads();

    if (tid == 0) {
        float l[NEXP];
#pragma unroll
        for (int e = 0; e < NEXP; ++e)
            l[e] = red2[0][e] + red2[1][e] + red2[2][e] + red2[3][e];
        int sel[TOPK];
        float selv[TOPK];
        bool used[NEXP] = {};
#pragma unroll
        for (int r = 0; r < TOPK; ++r) {
            int best = -1;
            float bv = -1e30f;
            for (int e = 0; e < NEXP; ++e)
                if (!used[e] && l[e] > bv) { bv = l[e]; best = e; }
            used[best] = true;
            sel[r] = best;
            selv[r] = bv;
        }
        float mx = selv[0];
        float wsum = 0.f, wvv[TOPK];
#pragma unroll
        for (int r = 0; r < TOPK; ++r) { wvv[r] = __expf(selv[r] - mx); wsum += wvv[r]; }
        float out16[NEXP] = {};
#pragma unroll
        for (int r = 0; r < TOPK; ++r) out16[sel[r]] = wvv[r] / wsum;
#pragma unroll
        for (int e = 0; e < NEXP; ++e) comb[(size_t)t * NEXP + e] = out16[e];
    }
}

// ---------------------------------------------------------------------------
extern "C" void kernel_launch(void* const* d_in, const int* in_sizes, int n_in,
                              void* d_out, int out_size, void* d_ws, size_t ws_size,
                              hipStream_t stream)
{
    const float* hidden   = (const float*)d_in[0];
    const float* residual = (const float*)d_in[1];
    const float* rms1_w   = (const float*)d_in[2];
    const float* rms2_w   = (const float*)d_in[3];
    const float* w_qkv    = (const float*)d_in[4];
    const float* w_dense  = (const float*)d_in[5];
    const float* gate_w   = (const float*)d_in[6];
    const float* w13      = (const float*)d_in[7];
    const float* w2       = (const float*)d_in[8];
    const float* sw13     = (const float*)d_in[9];
    const float* sw2      = (const float*)d_in[10];
    const int*   pos_ids  = (const int*)d_in[11];

    const int T = TT;

    float* out0 = (float*)d_out;
    float* out1 = (float*)d_out + (size_t)T * HD;

    // ---- workspace layout ----
    char* base = (char*)d_ws;
    float*          residF = (float*)(base);                    //  8.39 MB
    unsigned short* xB     = (unsigned short*)(base + 8388608); //  4.19 MB
    unsigned short* ctxB   = (unsigned short*)(base + 12582912);//  4.19 MB
    unsigned short* actC   = (unsigned short*)(base);           //  4.19 MB alias (residF dead by MoE)
    unsigned short* x2B    = (unsigned short*)(base + 29360128);//  4.19 MB
    unsigned short* sactB  = (unsigned short*)(base + 33554432);//  2.10 MB
    float*          comb   = (float*)(base + 35651584);         //  0.07 MB
    float*          part   = (float*)(base + 35717120);         // 33.55 MB (split-K / slot partials)
    unsigned short* Wbuf   = (unsigned short*)(base + 69271552);// 67.11 MB (weights, phase-reused)
    int*            lists  = (int*)(base + 139526144);          //  64 KB
    int*            cnts   = (int*)(base + 139591680);          //  256 B
    int*            slots  = (int*)(base + 139591936);          //  64 KB
    int*            bases  = (int*)(base + 139657472);          //  128 B

    // attention bf16 buffers live in the part region ABOVE the 2 qkv
    // partials (25.17 MB); Qb..Vt = 7 MB, total 32.2 <= 33.55.
    unsigned short* Qb = (unsigned short*)(base + 35717120 + 25165824);  // 4 MB
    unsigned short* Kb = Qb + (size_t)NQH * TT * HEADD;                  // 1 MB
    unsigned short* Vb = Kb + (size_t)NKVH * TT * HEADD;                 // 1 MB
    unsigned short* Vt = Vb + (size_t)NKVH * TT * HEADD;                 // 1 MB

    dim3 blk(256);

    // 1. resid = hidden + residual ; x = rmsnorm -> bf16
    add_rmsnorm_kernel<<<dim3(T), blk, 0, stream>>>(
        hidden, residual, rms1_w, residF, xB);

    // 2. qkv = x @ w_qkv   (split-K x2; reduce fused into rope_pack)
    transpose_convert<<<dim3(QKVN / 32, HD / 64), blk, 0, stream>>>(
        w_qkv, Wbuf, HD, QKVN, 0, 0);
    gemm_splitk<<<dim3(QKVN / 128, T / 128, 2), blk, 0, stream>>>(
        xB, Wbuf, part, T, QKVN, 1024, HD, HD);

    // 3. RoPE + fused 2-partial reduce + pack head-major bf16 ; V transpose
    rope_pack<<<dim3(T), blk, 0, stream>>>(
        part, part + (size_t)T * QKVN, pos_ids, Qb, Kb, Vb);
    transpose_v<<<dim3(T / 32, HEADD / 32, NKVH), blk, 0, stream>>>(Vb, Vt);

    // 4. MFMA flash attention v2 -> ctx (bf16)
    flash_attn_mfma<<<dim3(NQH, 8, 2), dim3(128), 0, stream>>>(Qb, Kb, Vt, ctxB);

    // 5+6. resid2 = ctx @ w_dense + resid ; x2 = rmsnorm  (fused reduce)
    transpose_convert<<<dim3(HD / 32, HD / 64), blk, 0, stream>>>(
        w_dense, Wbuf, HD, HD, 0, 0);
    gemm_splitk<<<dim3(HD / 128, T / 128, 4), blk, 0, stream>>>(
        ctxB, Wbuf, part, T, HD, 512, HD, HD);
    reduce4_add_rmsnorm<<<dim3(T), blk, 0, stream>>>(
        part, residF, rms2_w, out1, x2B);

    // 7. fused router -> comb ; 8. expert token lists + slots + bases
    router_fused<<<dim3(T), blk, 0, stream>>>(out1, rms2_w, gate_w, comb);
    build_lists<<<dim3(NEXP), blk, 0, stream>>>(comb, lists, slots, cnts);
    scan_cnts<<<dim3(1), dim3(64), 0, stream>>>(cnts, bases);

    // 9. shared gu = x2 @ sw13  (split-K x4) -> part
    transpose_convert<<<dim3(2 * SSI / 32, HD / 64), blk, 0, stream>>>(
        sw13, Wbuf, HD, 2 * SSI, 0, 0);
    gemm_splitk<<<dim3(HD / 128, T / 128, 4), blk, 0, stream>>>(
        x2B, Wbuf, part, T, 2 * SSI, 512, HD, HD);

    // 10. fused reduce + SwiGLU -> sactB (bf16)
    reduce_swiglu<<<dim3(T * SSI / 4 / 256), blk, 0, stream>>>(part, 4, sactB);

    // 11. out0 = shared_act @ sw2  (split-K x4)
    transpose_convert<<<dim3(HD / 32, SSI / 64), blk, 0, stream>>>(
        sw2, Wbuf, SSI, HD, 0, 0);
    gemm_splitk<<<dim3(HD / 128, T / 128, 4), blk, 0, stream>>>(
        sactB, Wbuf, part, T, HD, 256, SSI, SSI);
    reduce_partials<<<dim3(1024), blk, 0, stream>>>(
        part, 4, T * HD / 4, nullptr, out0, 0);

    // 12. sparse expert up + fused SwiGLU*comb -> compact actC
    transpose_convert<<<dim3(1024 / 32, HD / 64, NEXP), blk, 0, stream>>>(
        w13, Wbuf, HD, 1024, (long long)HD * 1024, (long long)1024 * HD);
    moe_up_gather<<<dim3(EI / 64, 16, NEXP), blk, 0, stream>>>(
        x2B, Wbuf, comb, lists, cnts, bases, actC);

    // 13. sparse down: actC @ w2T-slices -> 4 slot partials ; out0 += sum
    transpose_convert<<<dim3(HD / 32, (NEXP * EI) / 64), blk, 0, stream>>>(
        w2, Wbuf, NEXP * EI, HD, 0, 0);
    moe_down_gather<<<dim3(HD / 128, 16, NEXP), blk, 0, stream>>>(
        actC, Wbuf, lists, slots, cnts, bases, part);
    reduce_partials<<<dim3(1024), blk, 0, stream>>>(
        part, 4, T * HD / 4, nullptr, out0, 1);
}